// Round 1
// baseline (4080.233 us; speedup 1.0000x reference)
//
#include <hip/hip_runtime.h>

typedef _Float16 f16;
typedef _Float16 half8 __attribute__((ext_vector_type(8)));
typedef float floatx4 __attribute__((ext_vector_type(4)));

// Problem sizes
#define NB 64
#define NS 256
#define NE 512
#define NH 512
#define NG 2048   // 4H
#define NN 4096   // 2 dirs * 4H
#define NR 16384  // B*S

// ---------------- workspace layout (bytes) ----------------
// xp     : f16 [16384][4096]   134217728   gate preacts (bias folded), both dirs
// emb_h  : f16 [16384][512]     16777216
// w_cat  : f16 [4096][512]       4194304   [w_ih_f ; w_ih_b]
// whh    : f16 [2][2048][512]    4194304
// h_seq  : f16 [64][256][1024]  33554432   [h_f | h_b] for attention
// h_ex   : f16 [2][2][64][512]    262144   parity x dir x b x hu exchange buf
// bias   : f32 [4096]              16384   b_ih + b_hh per dir
// flags  : int [64*16]              4096   one cache line per block
#define OFF_XP     0
#define OFF_EMB    134217728
#define OFF_WCAT   150994944
#define OFF_WHH    155189248
#define OFF_HSEQ   159383552
#define OFF_HEX    192937984
#define OFF_BIAS   193200128
#define OFF_FLAGS  193216512

// ---------------- prep: zero exchange buffers, combine biases ----------------
__global__ void k_prep(uint4* hex4, int* flags, float* bias,
                       const float* bihf, const float* bhhf,
                       const float* bihb, const float* bhhb) {
  int id = blockIdx.x * 256 + threadIdx.x;       // 16384 threads
  uint4 z; z.x = 0; z.y = 0; z.z = 0; z.w = 0;
  hex4[id] = z;                                  // 262144 B == 16384 uint4
  if (id < 1024) flags[id] = 0;
  if (id < 4096)
    bias[id] = (id < 2048) ? (bihf[id] + bhhf[id]) : (bihb[id - 2048] + bhhb[id - 2048]);
}

// ---------------- embedding gather + f32->f16 cast ----------------
__global__ void k_embed(const int* __restrict__ x, const float* __restrict__ embed,
                        f16* __restrict__ emb_h) {
  int gid = blockIdx.x * 256 + threadIdx.x;      // 1048576 threads, 8 halves each
  size_t base = (size_t)gid * 8;
  int r = (int)(base >> 9);
  int e = (int)(base & 511);
  int xi = x[r];
  const float4* src = (const float4*)(embed + (size_t)xi * 512 + e);
  float4 a = src[0], b = src[1];
  half8 h;
  h[0] = (f16)a.x; h[1] = (f16)a.y; h[2] = (f16)a.z; h[3] = (f16)a.w;
  h[4] = (f16)b.x; h[5] = (f16)b.y; h[6] = (f16)b.z; h[7] = (f16)b.w;
  *(half8*)(emb_h + base) = h;
}

// ---------------- weight casts ----------------
__global__ void k_wcast(const float* __restrict__ wihf, const float* __restrict__ wihb,
                        const float* __restrict__ whhf, const float* __restrict__ whhb,
                        f16* __restrict__ w_cat, f16* __restrict__ whh) {
  int gid = blockIdx.x * 256 + threadIdx.x;      // 524288 threads, 8 halves each
  size_t i8 = (size_t)gid * 8;
  const float* src;
  f16* dst;
  if (i8 < 2097152) {                            // w_cat [4096][512]
    size_t n = i8 >> 9, k = i8 & 511;
    src = (n < 2048 ? wihf + n * 512 : wihb + (n - 2048) * 512) + k;
    dst = w_cat + i8;
  } else {                                       // whh [2][2048][512]
    size_t i2 = i8 - 2097152;
    int dir = (int)(i2 >> 20);
    size_t rk = i2 & 1048575;
    src = (dir ? whhb : whhf) + rk;
    dst = whh + i2;
  }
  float4 a = *(const float4*)src, b = *(const float4*)(src + 4);
  half8 h;
  h[0] = (f16)a.x; h[1] = (f16)a.y; h[2] = (f16)a.z; h[3] = (f16)a.w;
  h[4] = (f16)b.x; h[5] = (f16)b.y; h[6] = (f16)b.z; h[7] = (f16)b.w;
  *(half8*)dst = h;
}

// ---------------- xproj GEMM: [16384,512] @ [4096,512]^T -> f16, +bias ----------
// 128x128 tile, BK=32, 4 waves each doing 4x4 of 16x16x32_f16 MFMA.
__global__ __launch_bounds__(256) void k_gemm(const f16* __restrict__ A,
                                              const f16* __restrict__ Bw,
                                              const float* __restrict__ bias,
                                              f16* __restrict__ xp) {
  __shared__ __align__(16) f16 As[128 * 32];
  __shared__ __align__(16) f16 Bs[128 * 32];
  const int t = threadIdx.x;
  const int m0 = blockIdx.x * 128;
  const int n0 = blockIdx.y * 128;
  const int w = t >> 6, l = t & 63;
  const int wm = w >> 1, wn = w & 1;
  const int l15 = l & 15, q8 = (l >> 4) * 8;

  floatx4 acc[4][4];
#pragma unroll
  for (int mi = 0; mi < 4; mi++)
#pragma unroll
    for (int ni = 0; ni < 4; ni++) {
      acc[mi][ni][0] = 0.f; acc[mi][ni][1] = 0.f;
      acc[mi][ni][2] = 0.f; acc[mi][ni][3] = 0.f;
    }

  for (int kt = 0; kt < 16; kt++) {
#pragma unroll
    for (int i = 0; i < 2; i++) {
      int c = t + 256 * i;
      int row = c >> 2, kc = (c & 3) * 8;
      *(uint4*)&As[row * 32 + kc] = *(const uint4*)(A + (size_t)(m0 + row) * 512 + kt * 32 + kc);
      *(uint4*)&Bs[row * 32 + kc] = *(const uint4*)(Bw + (size_t)(n0 + row) * 512 + kt * 32 + kc);
    }
    __syncthreads();
    half8 af[4], bf[4];
#pragma unroll
    for (int mi = 0; mi < 4; mi++)
      af[mi] = *(const half8*)&As[(wm * 64 + mi * 16 + l15) * 32 + q8];
#pragma unroll
    for (int ni = 0; ni < 4; ni++)
      bf[ni] = *(const half8*)&Bs[(wn * 64 + ni * 16 + l15) * 32 + q8];
#pragma unroll
    for (int mi = 0; mi < 4; mi++)
#pragma unroll
      for (int ni = 0; ni < 4; ni++)
        acc[mi][ni] = __builtin_amdgcn_mfma_f32_16x16x32_f16(af[mi], bf[ni], acc[mi][ni], 0, 0, 0);
    __syncthreads();
  }

  // epilogue: C row=(l>>4)*4+reg, col=l&15 ; add bias, store f16
#pragma unroll
  for (int ni = 0; ni < 4; ni++) {
    int ng = n0 + wn * 64 + ni * 16 + l15;
    float bv = bias[ng];
#pragma unroll
    for (int mi = 0; mi < 4; mi++) {
      int mg = m0 + wm * 64 + mi * 16 + (l >> 4) * 4;
#pragma unroll
      for (int r = 0; r < 4; r++)
        xp[(size_t)(mg + r) * 4096 + ng] = (f16)(acc[mi][ni][r] + bv);
    }
  }
}

// ---------------- recurrent kernel ----------------
// 64 blocks: blk = dir + 2*j (dir in {0,1}, j in [0,32) = 16-hidden-unit chunk).
// Wave w of a block owns gate-type w (i,f,g,o) for hidden units [16j,16j+16):
// its w_hh rows live in VGPRs as 16 prebuilt MFMA A-frags for the whole kernel.
// Per step: z[g][b] = sum_k w[g][k]*h[b][k] via 64 MFMAs/wave, + xp (+bias inside),
// LDS exchange of i/f/g/o, per-thread c update (c in VGPRs), publish h chunk to
// double-buffered global h_ex, release flag; peers poll flags + acquire fence.
__global__ __launch_bounds__(256) void k_rec(const f16* __restrict__ whh,
                                             const f16* __restrict__ xp,
                                             f16* __restrict__ h_ex,
                                             f16* __restrict__ h_seq,
                                             int* flags) {
  const int blk = blockIdx.x;
  const int dir = blk & 1, j = blk >> 1;
  const int t = threadIdx.x;
  const int w = t >> 6, l = t & 63;
  const int l15 = l & 15, q = l >> 4;

  // preload weight A-frags: A[m=l&15][k=q*8+jj], rows = gate-type w, hu chunk j
  const f16* wb = whh + ((size_t)dir * NG + (size_t)w * 512 + j * 16 + l15) * 512;
  half8 fa[16];
#pragma unroll
  for (int kt = 0; kt < 16; kt++) fa[kt] = *(const half8*)(wb + kt * 32 + q * 8);

  __shared__ float zbuf[4][16][65];            // [gate_type][m][b], padded
  __shared__ __align__(16) f16 hstage[64][16]; // [b][hu_local]

  float creg[4] = {0.f, 0.f, 0.f, 0.f};
  const int hu = t >> 4, b0 = (t & 15) * 4;    // update-phase cell ownership
  const int cb = t >> 2, cq = t & 3;           // copy-phase mapping

  size_t xrow[4];
  {
    size_t col0 = (size_t)dir * NG + (size_t)w * 512 + j * 16 + q * 4;
#pragma unroll
    for (int ni = 0; ni < 4; ni++)
      xrow[ni] = (size_t)(16 * ni + l15) * NS * NN + col0;
  }

#pragma unroll 1
  for (int st = 0; st < NS; st++) {
    if (st > 0) {
      while (true) {
        int f = (l < 32)
                    ? __hip_atomic_load(&flags[(dir + 2 * l) * 16], __ATOMIC_RELAXED,
                                        __HIP_MEMORY_SCOPE_AGENT)
                    : st;
        if (__ballot(f >= st) == ~0ull) break;
        __builtin_amdgcn_s_sleep(2);
      }
      __builtin_amdgcn_fence(__ATOMIC_ACQUIRE, "agent");
    }
    const int s = dir ? (255 - st) : st;

    // xproj (bias already folded): 4 halves per ni, consecutive
    float xv[4][4];
#pragma unroll
    for (int ni = 0; ni < 4; ni++) {
      uint2 raw = *(const uint2*)(xp + xrow[ni] + (size_t)s * NN);
      const f16* hp = (const f16*)&raw;
#pragma unroll
      for (int r = 0; r < 4; r++) xv[ni][r] = (float)hp[r];
    }

    // z = w_hh @ h  (B-frags read straight from global exchange buffer)
    const f16* hb = h_ex + (size_t)((st & 1) * 2 + dir) * 64 * 512;
    floatx4 acc[4];
#pragma unroll
    for (int ni = 0; ni < 4; ni++) {
      acc[ni][0] = 0.f; acc[ni][1] = 0.f; acc[ni][2] = 0.f; acc[ni][3] = 0.f;
    }
#pragma unroll
    for (int kt = 0; kt < 16; kt++) {
#pragma unroll
      for (int ni = 0; ni < 4; ni++) {
        half8 bf = *(const half8*)(hb + (size_t)(16 * ni + l15) * 512 + kt * 32 + q * 8);
        acc[ni] = __builtin_amdgcn_mfma_f32_16x16x32_f16(fa[kt], bf, acc[ni], 0, 0, 0);
      }
    }

    // z + xp -> LDS for gate exchange
#pragma unroll
    for (int ni = 0; ni < 4; ni++)
#pragma unroll
      for (int r = 0; r < 4; r++)
        zbuf[w][q * 4 + r][16 * ni + l15] = acc[ni][r] + xv[ni][r];
    __syncthreads();

    // LSTM cell update; c persistent in VGPRs
    float hnew[4];
#pragma unroll
    for (int bb = 0; bb < 4; bb++) {
      int b = b0 + bb;
      float iv = zbuf[0][hu][b];
      float fv = zbuf[1][hu][b];
      float gv = zbuf[2][hu][b];
      float ov = zbuf[3][hu][b];
      float ig = 1.f / (1.f + __expf(-iv));
      float fg = 1.f / (1.f + __expf(-fv));
      float og = 1.f / (1.f + __expf(-ov));
      float c = fg * creg[bb] + ig * tanhf(gv);
      creg[bb] = c;
      hnew[bb] = og * tanhf(c);
    }
#pragma unroll
    for (int bb = 0; bb < 4; bb++) hstage[b0 + bb][hu] = (f16)hnew[bb];
    __syncthreads();

    // publish h chunk (double-buffered) + h_seq for attention
    uint2 v = *(const uint2*)&hstage[cb][cq * 4];
    *(uint2*)(h_ex + ((size_t)(((st + 1) & 1) * 2 + dir) * 64 + cb) * 512 + j * 16 + cq * 4) = v;
    *(uint2*)(h_seq + ((size_t)cb * NS + s) * 1024 + (size_t)dir * 512 + j * 16 + cq * 4) = v;
    __syncthreads();  // drains vmcnt: all stores at least in L2

    if (t == 0) {
      __threadfence();  // agent fence: write back L2 so peers' acquire sees h
      __hip_atomic_store(&flags[blk * 16], st + 1, __ATOMIC_RELAXED, __HIP_MEMORY_SCOPE_AGENT);
    }
  }
}

// ---------------- attention pooling + lin1 + lin2 ----------------
__global__ __launch_bounds__(256) void k_attn(const f16* __restrict__ h_seq,
                                              const float* __restrict__ myw,
                                              const float* __restrict__ l1w,
                                              const float* __restrict__ l1b,
                                              const float* __restrict__ l2w,
                                              const float* __restrict__ l2b,
                                              float* __restrict__ out) {
  const int b = blockIdx.x;
  const int t = threadIdx.x;
  const int w = t >> 6, l = t & 63;
  float mw[16];
#pragma unroll
  for (int i = 0; i < 16; i += 4) {
    float4 v = *(const float4*)(myw + l * 16 + i);
    mw[i] = v.x; mw[i + 1] = v.y; mw[i + 2] = v.z; mw[i + 3] = v.w;
  }
  float pool[16];
#pragma unroll
  for (int i = 0; i < 16; i++) pool[i] = 0.f;
  float psum = 0.f;

  for (int s = w; s < NS; s += 4) {   // each wave owns s % 4 == w
    const f16* hp = h_seq + ((size_t)b * NS + s) * 1024 + l * 16;
    half8 h0 = *(const half8*)hp;
    half8 h1 = *(const half8*)(hp + 8);
    float hv[16];
#pragma unroll
    for (int i = 0; i < 8; i++) { hv[i] = (float)h0[i]; hv[8 + i] = (float)h1[i]; }
    float d = 0.f;
#pragma unroll
    for (int i = 0; i < 16; i++) d += hv[i] * mw[i];
#pragma unroll
    for (int off = 32; off > 0; off >>= 1) d += __shfl_xor(d, off);
    float p = __expf(tanhf(d));
    psum += p;
#pragma unroll
    for (int i = 0; i < 16; i++) pool[i] += p * hv[i];
  }

  __shared__ float zb[4][1024];
  __shared__ float ps[4];
  __shared__ float pooled[1024];
  __shared__ float h1s[512];
#pragma unroll
  for (int i = 0; i < 16; i++) zb[w][l * 16 + i] = pool[i];
  if (l == 0) ps[w] = psum;
  __syncthreads();
  float denom = ps[0] + ps[1] + ps[2] + ps[3];
  for (int d0 = t; d0 < 1024; d0 += 256)
    pooled[d0] = (zb[0][d0] + zb[1][d0] + zb[2][d0] + zb[3][d0]) / denom;
  __syncthreads();
  for (int r = t; r < 512; r += 256) {
    const float* wr = l1w + (size_t)r * 1024;
    float a = l1b[r];
    for (int k = 0; k < 1024; k += 4) {
      float4 wv = *(const float4*)(wr + k);
      a += wv.x * pooled[k] + wv.y * pooled[k + 1] + wv.z * pooled[k + 2] + wv.w * pooled[k + 3];
    }
    h1s[r] = a;
  }
  __syncthreads();
  if (t < 20) {
    const float* wr = l2w + t * 512;
    float a = l2b[t];
    for (int k = 0; k < 512; k++) a += h1s[k] * wr[k];
    out[b * 20 + t] = a;
  }
}

extern "C" void kernel_launch(void* const* d_in, const int* in_sizes, int n_in,
                              void* d_out, int out_size, void* d_ws, size_t ws_size,
                              hipStream_t stream) {
  (void)in_sizes; (void)n_in; (void)out_size; (void)ws_size;
  const int*   x     = (const int*)d_in[0];
  const float* embed = (const float*)d_in[1];
  const float* wihf  = (const float*)d_in[2];
  const float* whhf  = (const float*)d_in[3];
  const float* bihf  = (const float*)d_in[4];
  const float* bhhf  = (const float*)d_in[5];
  const float* wihb  = (const float*)d_in[6];
  const float* whhb  = (const float*)d_in[7];
  const float* bihb  = (const float*)d_in[8];
  const float* bhhb  = (const float*)d_in[9];
  const float* myw   = (const float*)d_in[10];
  const float* l1w   = (const float*)d_in[11];
  const float* l1b   = (const float*)d_in[12];
  const float* l2w   = (const float*)d_in[13];
  const float* l2b   = (const float*)d_in[14];

  char* ws = (char*)d_ws;
  f16*   xp    = (f16*)(ws + OFF_XP);
  f16*   emb_h = (f16*)(ws + OFF_EMB);
  f16*   w_cat = (f16*)(ws + OFF_WCAT);
  f16*   whh   = (f16*)(ws + OFF_WHH);
  f16*   h_seq = (f16*)(ws + OFF_HSEQ);
  f16*   h_ex  = (f16*)(ws + OFF_HEX);
  float* bias  = (float*)(ws + OFF_BIAS);
  int*   flags = (int*)(ws + OFF_FLAGS);
  float* out   = (float*)d_out;

  k_prep<<<64, 256, 0, stream>>>((uint4*)h_ex, flags, bias, bihf, bhhf, bihb, bhhb);
  k_embed<<<4096, 256, 0, stream>>>(x, embed, emb_h);
  k_wcast<<<2048, 256, 0, stream>>>(wihf, wihb, whhf, whhb, w_cat, whh);
  k_gemm<<<dim3(128, 32), 256, 0, stream>>>(emb_h, w_cat, bias, xp);
  k_rec<<<64, 256, 0, stream>>>(whh, xp, h_ex, h_seq, flags);
  k_attn<<<64, 256, 0, stream>>>(h_seq, myw, l1w, l1b, l2w, l2b, out);
}

// Round 2
// 1304.384 us; speedup vs baseline: 3.1281x; 3.1281x over previous
//
#include <hip/hip_runtime.h>

typedef _Float16 f16;
typedef _Float16 half8 __attribute__((ext_vector_type(8)));
typedef float floatx4 __attribute__((ext_vector_type(4)));
typedef unsigned long long u64;

// Problem sizes
#define NB 64
#define NS 256
#define NE 512
#define NH 512
#define NG 2048   // 4H
#define NN 4096   // 2 dirs * 4H

// ---------------- workspace layout (bytes) ----------------
// xp     : f16 [16384][4096]   134217728   gate preacts (bias folded), both dirs
// emb_h  : f16 [16384][512]     16777216
// w_cat  : f16 [4096][512]       4194304   [w_ih_f ; w_ih_b]
// whh    : f16 [2][2048][512]    4194304
// h_seq  : f16 [64][256][1024]  33554432   [h_f | h_b] for attention
// h_ex   : f16 [2par][2dir][8bg][8b][512]  262144  IF-coherent exchange buffer
// bias   : f32 [4096]              16384
// flags  : int [256*16]            16384   one 64B line per (dir,bg,jg)
#define OFF_XP     0
#define OFF_EMB    134217728
#define OFF_WCAT   150994944
#define OFF_WHH    155189248
#define OFF_HSEQ   159383552
#define OFF_HEX    192937984
#define OFF_BIAS   193200128
#define OFF_FLAGS  193216512

__device__ __forceinline__ void waitvm0() {
  asm volatile("s_waitcnt vmcnt(0)" ::: "memory");
}
__device__ __forceinline__ void cbar() {  // compiler-only reorder barrier
  asm volatile("" ::: "memory");
}

// ---------------- prep: zero exchange buffers, combine biases ----------------
__global__ void k_prep(uint4* hex4, int* flags, float* bias,
                       const float* bihf, const float* bhhf,
                       const float* bihb, const float* bhhb) {
  int id = blockIdx.x * 256 + threadIdx.x;       // 16384 threads
  uint4 z; z.x = 0; z.y = 0; z.z = 0; z.w = 0;
  hex4[id] = z;                                  // 262144 B == 16384 uint4
  if (id < 4096) flags[id] = 0;
  if (id < 4096)
    bias[id] = (id < 2048) ? (bihf[id] + bhhf[id]) : (bihb[id - 2048] + bhhb[id - 2048]);
}

// ---------------- embedding gather + f32->f16 cast ----------------
__global__ void k_embed(const int* __restrict__ x, const float* __restrict__ embed,
                        f16* __restrict__ emb_h) {
  int gid = blockIdx.x * 256 + threadIdx.x;      // 1048576 threads, 8 halves each
  size_t base = (size_t)gid * 8;
  int r = (int)(base >> 9);
  int e = (int)(base & 511);
  int xi = x[r];
  const float4* src = (const float4*)(embed + (size_t)xi * 512 + e);
  float4 a = src[0], b = src[1];
  half8 h;
  h[0] = (f16)a.x; h[1] = (f16)a.y; h[2] = (f16)a.z; h[3] = (f16)a.w;
  h[4] = (f16)b.x; h[5] = (f16)b.y; h[6] = (f16)b.z; h[7] = (f16)b.w;
  *(half8*)(emb_h + base) = h;
}

// ---------------- weight casts ----------------
__global__ void k_wcast(const float* __restrict__ wihf, const float* __restrict__ wihb,
                        const float* __restrict__ whhf, const float* __restrict__ whhb,
                        f16* __restrict__ w_cat, f16* __restrict__ whh) {
  int gid = blockIdx.x * 256 + threadIdx.x;      // 524288 threads, 8 halves each
  size_t i8 = (size_t)gid * 8;
  const float* src;
  f16* dst;
  if (i8 < 2097152) {                            // w_cat [4096][512]
    size_t n = i8 >> 9, k = i8 & 511;
    src = (n < 2048 ? wihf + n * 512 : wihb + (n - 2048) * 512) + k;
    dst = w_cat + i8;
  } else {                                       // whh [2][2048][512]
    size_t i2 = i8 - 2097152;
    int dir = (int)(i2 >> 20);
    size_t rk = i2 & 1048575;
    src = (dir ? whhb : whhf) + rk;
    dst = whh + i2;
  }
  float4 a = *(const float4*)src, b = *(const float4*)(src + 4);
  half8 h;
  h[0] = (f16)a.x; h[1] = (f16)a.y; h[2] = (f16)a.z; h[3] = (f16)a.w;
  h[4] = (f16)b.x; h[5] = (f16)b.y; h[6] = (f16)b.z; h[7] = (f16)b.w;
  *(half8*)dst = h;
}

// ---------------- xproj GEMM: [16384,512] @ [4096,512]^T -> f16, +bias ----------
__global__ __launch_bounds__(256) void k_gemm(const f16* __restrict__ A,
                                              const f16* __restrict__ Bw,
                                              const float* __restrict__ bias,
                                              f16* __restrict__ xp) {
  __shared__ __align__(16) f16 As[128 * 32];
  __shared__ __align__(16) f16 Bs[128 * 32];
  const int t = threadIdx.x;
  const int m0 = blockIdx.x * 128;
  const int n0 = blockIdx.y * 128;
  const int w = t >> 6, l = t & 63;
  const int wm = w >> 1, wn = w & 1;
  const int l15 = l & 15, q8 = (l >> 4) * 8;

  floatx4 acc[4][4];
#pragma unroll
  for (int mi = 0; mi < 4; mi++)
#pragma unroll
    for (int ni = 0; ni < 4; ni++) {
      acc[mi][ni][0] = 0.f; acc[mi][ni][1] = 0.f;
      acc[mi][ni][2] = 0.f; acc[mi][ni][3] = 0.f;
    }

  for (int kt = 0; kt < 16; kt++) {
#pragma unroll
    for (int i = 0; i < 2; i++) {
      int c = t + 256 * i;
      int row = c >> 2, kc = (c & 3) * 8;
      *(uint4*)&As[row * 32 + kc] = *(const uint4*)(A + (size_t)(m0 + row) * 512 + kt * 32 + kc);
      *(uint4*)&Bs[row * 32 + kc] = *(const uint4*)(Bw + (size_t)(n0 + row) * 512 + kt * 32 + kc);
    }
    __syncthreads();
    half8 af[4], bf[4];
#pragma unroll
    for (int mi = 0; mi < 4; mi++)
      af[mi] = *(const half8*)&As[(wm * 64 + mi * 16 + l15) * 32 + q8];
#pragma unroll
    for (int ni = 0; ni < 4; ni++)
      bf[ni] = *(const half8*)&Bs[(wn * 64 + ni * 16 + l15) * 32 + q8];
#pragma unroll
    for (int mi = 0; mi < 4; mi++)
#pragma unroll
      for (int ni = 0; ni < 4; ni++)
        acc[mi][ni] = __builtin_amdgcn_mfma_f32_16x16x32_f16(af[mi], bf[ni], acc[mi][ni], 0, 0, 0);
    __syncthreads();
  }

#pragma unroll
  for (int ni = 0; ni < 4; ni++) {
    int ng = n0 + wn * 64 + ni * 16 + l15;
    float bv = bias[ng];
#pragma unroll
    for (int mi = 0; mi < 4; mi++) {
      int mg = m0 + wm * 64 + mi * 16 + (l >> 4) * 4;
#pragma unroll
      for (int r = 0; r < 4; r++)
        xp[(size_t)(mg + r) * 4096 + ng] = (f16)(acc[mi][ni][r] + bv);
    }
  }
}

// ---------------- recurrent kernel ----------------
// 256 blocks: blk = dir + 2*bg + 16*jg. dir in {0,1}; bg = batch group (8 batches);
// jg = hidden-unit chunk (32 hu). Wave w owns gate type w (i,f,g,o).
// w_hh rows for (dir, gate w, hu chunk jg) live in VGPRs (fa, 128 VGPR/lane).
// Sync group = 16 blocks sharing (dir,bg). All cross-block traffic (h_ex, flags)
// uses system-scope relaxed atomics -> sc0 sc1 ops served coherently at the
// Infinity Cache. NO acquire/release fences (no buffer_inv / buffer_wbl2):
// release = s_waitcnt vmcnt(0) between data stores and flag store; acquire =
// control dependence (loads issue after the poll branch resolves, in-order HW).
__global__ __launch_bounds__(256) void k_rec(const f16* __restrict__ whh,
                                             const f16* __restrict__ xp,
                                             f16* __restrict__ h_ex,
                                             f16* __restrict__ h_seq,
                                             int* flags) {
  const int blk = blockIdx.x;
  const int dir = blk & 1;
  const int bg  = (blk >> 1) & 7;
  const int jg  = blk >> 4;
  const int t = threadIdx.x;
  const int w = t >> 6, l = t & 63;
  const int l15 = l & 15, q = l >> 4;
  const int lb = l15 & 7;                 // batch row, clamped (cols 8-15 dup/discarded)

  // A-frags: 32 w_hh rows per wave (2 m-tiles of 16), resident whole kernel
  half8 fa[2][16];
  {
    const f16* wb = whh + ((size_t)dir * 2048 + w * 512 + jg * 32 + l15) * 512;
#pragma unroll
    for (int mi = 0; mi < 2; mi++)
#pragma unroll
      for (int kt = 0; kt < 16; kt++)
        fa[mi][kt] = *(const half8*)(wb + (size_t)mi * 16 * 512 + kt * 32 + q * 8);
  }

  __shared__ __align__(16) f16 hbuf[4096];     // swizzled [kt16][b8][q4][8]
  __shared__ float zbuf[4][32][19];            // [gate][hu_local][b(pad)]
  __shared__ __align__(16) f16 hstage[8][32];  // [b][hu_local]

  float creg = 0.f;
  const int uhu = t & 31, ub = t >> 5;         // cell-update mapping (256 cells)

  // xp address: row=(8bg+lb)*256+s, col=dir*2048+w*512+jg*32 + mi*16 + q*4
  const size_t xrowb = ((size_t)(8 * bg + lb) * 256) * (size_t)NN +
                       (size_t)dir * 2048 + w * 512 + jg * 32 + q * 4;

  int* myflag = flags + ((dir * 8 + bg) * 16 + jg) * 16;
  int* gflags = flags + ((dir * 8 + bg) * 16) * 16;

  // cooperative h load mapping: thread t covers global halves [16t,16t+16)
  const int cl_b = t >> 5;
  const int cl_hu0 = (t & 31) * 16;
  const int cl_dst = (cl_hu0 >> 5) * 256 + cl_b * 32 + (cl_hu0 & 31);  // halves
  const int cl_src = cl_b * 512 + cl_hu0;                              // halves

#pragma unroll 1
  for (int st = 0; st < NS; st++) {
    const int s = dir ? (255 - st) : st;

    // prefetch xp (hides HBM latency under the poll)
    const f16* xpp = xp + xrowb + (size_t)s * NN;
    uint2 xv0 = *(const uint2*)xpp;
    uint2 xv1 = *(const uint2*)(xpp + 16);
    cbar();

    if (st > 0) {
      while (true) {
        int f = (l < 16)
                    ? __hip_atomic_load(&gflags[l * 16], __ATOMIC_RELAXED,
                                        __HIP_MEMORY_SCOPE_SYSTEM)
                    : st;
        if (__ballot(f >= st) == ~0ull) break;
        __builtin_amdgcn_s_sleep(1);
      }
    }
    cbar();

    // cooperative h load (32 B/thread, IF-coherent) -> swizzled LDS
    {
      const f16* slab = h_ex + (size_t)(((st & 1) * 2 + dir) * 8 + bg) * 4096;
      const u64* sp = (const u64*)(slab + cl_src);
      u64 h0 = __hip_atomic_load(sp + 0, __ATOMIC_RELAXED, __HIP_MEMORY_SCOPE_SYSTEM);
      u64 h1 = __hip_atomic_load(sp + 1, __ATOMIC_RELAXED, __HIP_MEMORY_SCOPE_SYSTEM);
      u64 h2 = __hip_atomic_load(sp + 2, __ATOMIC_RELAXED, __HIP_MEMORY_SCOPE_SYSTEM);
      u64 h3 = __hip_atomic_load(sp + 3, __ATOMIC_RELAXED, __HIP_MEMORY_SCOPE_SYSTEM);
      *(u64*)&hbuf[cl_dst + 0]  = h0;
      *(u64*)&hbuf[cl_dst + 4]  = h1;
      *(u64*)&hbuf[cl_dst + 8]  = h2;
      *(u64*)&hbuf[cl_dst + 12] = h3;
    }
    __syncthreads();

    // z = w_hh @ h : 32 MFMAs/wave, frag reads from swizzled LDS
    floatx4 acc[2];
    acc[0][0] = 0.f; acc[0][1] = 0.f; acc[0][2] = 0.f; acc[0][3] = 0.f;
    acc[1][0] = 0.f; acc[1][1] = 0.f; acc[1][2] = 0.f; acc[1][3] = 0.f;
#pragma unroll
    for (int kt = 0; kt < 16; kt++) {
      half8 bf = *(const half8*)&hbuf[kt * 256 + lb * 32 + q * 8];
      acc[0] = __builtin_amdgcn_mfma_f32_16x16x32_f16(fa[0][kt], bf, acc[0], 0, 0, 0);
      acc[1] = __builtin_amdgcn_mfma_f32_16x16x32_f16(fa[1][kt], bf, acc[1], 0, 0, 0);
    }

    // z + xp -> LDS gate exchange (D layout: row=q*4+r, col=l15)
    {
      const f16* x0 = (const f16*)&xv0;
      const f16* x1 = (const f16*)&xv1;
#pragma unroll
      for (int r = 0; r < 4; r++) {
        zbuf[w][q * 4 + r][l15]      = acc[0][r] + (float)x0[r];
        zbuf[w][16 + q * 4 + r][l15] = acc[1][r] + (float)x1[r];
      }
    }
    __syncthreads();

    // LSTM cell update: 1 cell/thread, c persistent in VGPR
    {
      float iv = zbuf[0][uhu][ub];
      float fv = zbuf[1][uhu][ub];
      float gv = zbuf[2][uhu][ub];
      float ov = zbuf[3][uhu][ub];
      float ig = 1.f / (1.f + __expf(-iv));
      float fg = 1.f / (1.f + __expf(-fv));
      float og = 1.f / (1.f + __expf(-ov));
      creg = fg * creg + ig * tanhf(gv);
      hstage[ub][uhu] = (f16)(og * tanhf(creg));
    }
    __syncthreads();

    // publish h chunk (IF-coherent, double-buffered) + h_seq; release via vmcnt
    if (t < 64) {
      const int pb = t >> 3, pc = (t & 7) * 4;
      u64 hv = *(const u64*)&hstage[pb][pc];
      f16* wslab = h_ex + (size_t)((((st + 1) & 1) * 2 + dir) * 8 + bg) * 4096;
      __hip_atomic_store((u64*)(wslab + pb * 512 + jg * 32 + pc), hv,
                         __ATOMIC_RELAXED, __HIP_MEMORY_SCOPE_SYSTEM);
      *(u64*)(h_seq + ((size_t)(8 * bg + pb) * 256 + s) * 1024 + dir * 512 + jg * 32 + pc) = hv;
      waitvm0();
      if (t == 0)
        __hip_atomic_store(myflag, st + 1, __ATOMIC_RELAXED, __HIP_MEMORY_SCOPE_SYSTEM);
    }
  }
}

// ---------------- attention pooling + lin1 + lin2 ----------------
__global__ __launch_bounds__(256) void k_attn(const f16* __restrict__ h_seq,
                                              const float* __restrict__ myw,
                                              const float* __restrict__ l1w,
                                              const float* __restrict__ l1b,
                                              const float* __restrict__ l2w,
                                              const float* __restrict__ l2b,
                                              float* __restrict__ out) {
  const int b = blockIdx.x;
  const int t = threadIdx.x;
  const int w = t >> 6, l = t & 63;
  float mw[16];
#pragma unroll
  for (int i = 0; i < 16; i += 4) {
    float4 v = *(const float4*)(myw + l * 16 + i);
    mw[i] = v.x; mw[i + 1] = v.y; mw[i + 2] = v.z; mw[i + 3] = v.w;
  }
  float pool[16];
#pragma unroll
  for (int i = 0; i < 16; i++) pool[i] = 0.f;
  float psum = 0.f;

  for (int s = w; s < NS; s += 4) {
    const f16* hp = h_seq + ((size_t)b * NS + s) * 1024 + l * 16;
    half8 h0 = *(const half8*)hp;
    half8 h1 = *(const half8*)(hp + 8);
    float hv[16];
#pragma unroll
    for (int i = 0; i < 8; i++) { hv[i] = (float)h0[i]; hv[8 + i] = (float)h1[i]; }
    float d = 0.f;
#pragma unroll
    for (int i = 0; i < 16; i++) d += hv[i] * mw[i];
#pragma unroll
    for (int off = 32; off > 0; off >>= 1) d += __shfl_xor(d, off);
    float p = __expf(tanhf(d));
    psum += p;
#pragma unroll
    for (int i = 0; i < 16; i++) pool[i] += p * hv[i];
  }

  __shared__ float zb[4][1024];
  __shared__ float ps[4];
  __shared__ float pooled[1024];
  __shared__ float h1s[512];
#pragma unroll
  for (int i = 0; i < 16; i++) zb[w][l * 16 + i] = pool[i];
  if (l == 0) ps[w] = psum;
  __syncthreads();
  float denom = ps[0] + ps[1] + ps[2] + ps[3];
  for (int d0 = t; d0 < 1024; d0 += 256)
    pooled[d0] = (zb[0][d0] + zb[1][d0] + zb[2][d0] + zb[3][d0]) / denom;
  __syncthreads();
  for (int r = t; r < 512; r += 256) {
    const float* wr = l1w + (size_t)r * 1024;
    float a = l1b[r];
    for (int k = 0; k < 1024; k += 4) {
      float4 wv = *(const float4*)(wr + k);
      a += wv.x * pooled[k] + wv.y * pooled[k + 1] + wv.z * pooled[k + 2] + wv.w * pooled[k + 3];
    }
    h1s[r] = a;
  }
  __syncthreads();
  if (t < 20) {
    const float* wr = l2w + t * 512;
    float a = l2b[t];
    for (int k = 0; k < 512; k++) a += h1s[k] * wr[k];
    out[b * 20 + t] = a;
  }
}

extern "C" void kernel_launch(void* const* d_in, const int* in_sizes, int n_in,
                              void* d_out, int out_size, void* d_ws, size_t ws_size,
                              hipStream_t stream) {
  (void)in_sizes; (void)n_in; (void)out_size; (void)ws_size;
  const int*   x     = (const int*)d_in[0];
  const float* embed = (const float*)d_in[1];
  const float* wihf  = (const float*)d_in[2];
  const float* whhf  = (const float*)d_in[3];
  const float* bihf  = (const float*)d_in[4];
  const float* bhhf  = (const float*)d_in[5];
  const float* wihb  = (const float*)d_in[6];
  const float* whhb  = (const float*)d_in[7];
  const float* bihb  = (const float*)d_in[8];
  const float* bhhb  = (const float*)d_in[9];
  const float* myw   = (const float*)d_in[10];
  const float* l1w   = (const float*)d_in[11];
  const float* l1b   = (const float*)d_in[12];
  const float* l2w   = (const float*)d_in[13];
  const float* l2b   = (const float*)d_in[14];

  char* ws = (char*)d_ws;
  f16*   xp    = (f16*)(ws + OFF_XP);
  f16*   emb_h = (f16*)(ws + OFF_EMB);
  f16*   w_cat = (f16*)(ws + OFF_WCAT);
  f16*   whh   = (f16*)(ws + OFF_WHH);
  f16*   h_seq = (f16*)(ws + OFF_HSEQ);
  f16*   h_ex  = (f16*)(ws + OFF_HEX);
  float* bias  = (float*)(ws + OFF_BIAS);
  int*   flags = (int*)(ws + OFF_FLAGS);
  float* out   = (float*)d_out;

  k_prep<<<64, 256, 0, stream>>>((uint4*)h_ex, flags, bias, bihf, bhhf, bihb, bhhb);
  k_embed<<<4096, 256, 0, stream>>>(x, embed, emb_h);
  k_wcast<<<2048, 256, 0, stream>>>(wihf, wihb, whhf, whhb, w_cat, whh);
  k_gemm<<<dim3(128, 32), 256, 0, stream>>>(emb_h, w_cat, bias, xp);
  k_rec<<<256, 256, 0, stream>>>(whh, xp, h_ex, h_seq, flags);
  k_attn<<<64, 256, 0, stream>>>(h_seq, myw, l1w, l1b, l2w, l2b, out);
}